// Round 7
// baseline (410.057 us; speedup 1.0000x reference)
//
#include <hip/hip_runtime.h>

typedef __bf16 bf16_t;
typedef bf16_t bf16x8 __attribute__((ext_vector_type(8)));
typedef bf16_t bf16x4 __attribute__((ext_vector_type(4)));
typedef float f32x4 __attribute__((ext_vector_type(4)));

// async global->LDS 16B per lane. LDS dest = wave-uniform base + lane*16
// (m97/m104): per-lane pointers must be linear in lane index.
__device__ __forceinline__ void async_copy16(const void* g, void* l) {
  __builtin_amdgcn_global_load_lds(
      (const __attribute__((address_space(1))) unsigned int*)(unsigned long long)g,
      (__attribute__((address_space(3))) unsigned int*)(unsigned int)(unsigned long long)l,
      16, 0, 0);
}

__device__ __forceinline__ float fast_exp2(float x) {
#if __has_builtin(__builtin_amdgcn_exp2f)
  return __builtin_amdgcn_exp2f(x);
#else
  return exp2f(x);
#endif
}

__device__ __forceinline__ unsigned pack_bf16(float x, float y) {
  bf16_t lo = (bf16_t)x, hi = (bf16_t)y;
  unsigned short ul, uh;
  __builtin_memcpy(&ul, &lo, 2);
  __builtin_memcpy(&uh, &hi, 2);
  return (unsigned)ul | ((unsigned)uh << 16);
}

// ------- cast x,h,W1 f32 -> bf16 (dst regions contiguous: xb|hb|w1bf) -------
__global__ __launch_bounds__(256) void cast3_bf16_kernel(
    const float* __restrict__ a, const float* __restrict__ b,
    const float* __restrict__ w1, bf16_t* __restrict__ dst) {
  int i = (blockIdx.x * 256 + threadIdx.x) * 8;  // [0, 9M)
  const float* s = (i < 4194304) ? (a + i)
                 : (i < 8388608) ? (b + i - 4194304)
                                 : (w1 + i - 8388608);
  float4 u = *(const float4*)s;
  float4 v = *(const float4*)(s + 4);
  bf16x8 o;
  o[0]=(bf16_t)u.x; o[1]=(bf16_t)u.y; o[2]=(bf16_t)u.z; o[3]=(bf16_t)u.w;
  o[4]=(bf16_t)v.x; o[5]=(bf16_t)v.y; o[6]=(bf16_t)v.z; o[7]=(bf16_t)v.w;
  *(bf16x8*)(dst + i) = o;
}

// ---------------- all-weights transpose+cast+scale (grid.z = weight idx) ----
struct SrcPtrs { const float* p[10]; };
__global__ __launch_bounds__(256) void transpose_cast_all(
    SrcPtrs srcs, bf16_t* __restrict__ dstbase) {
  __shared__ float tile[32][33];
  int z = blockIdx.z;
  const float* src = srcs.p[z];
  bf16_t* dst = dstbase + (size_t)z * 1048576;
  float scale = (z == 0) ? 0.125f : ((z == 4) ? 0.03125f : 1.f);
  int bx = blockIdx.x * 32;  // n base
  int by = blockIdx.y * 32;  // k base
  int tx = threadIdx.x, ty = threadIdx.y;
#pragma unroll
  for (int i = 0; i < 32; i += 8)
    tile[ty + i][tx] = src[(size_t)(by + ty + i) * 1024 + bx + tx];
  __syncthreads();
#pragma unroll
  for (int i = 0; i < 32; i += 8)
    dst[(size_t)(bx + ty + i) * 1024 + by + tx] = (bf16_t)(tile[tx][ty + i] * scale);
}

// --------- bias concat (+scale fold): [q|k|v|ck|cv|cq|zeros] x1024 ----------
__global__ __launch_bounds__(256) void prep_bias_kernel(
    const float* __restrict__ bq, const float* __restrict__ bk,
    const float* __restrict__ bv, const float* __restrict__ bck,
    const float* __restrict__ bcv, const float* __restrict__ bcq,
    float* __restrict__ cb) {
  int i = blockIdx.x * 256 + threadIdx.x;
  if (i < 1024) cb[i] = bq[i] * 0.125f;
  else if (i < 2048) cb[i] = bk[i - 1024];
  else if (i < 3072) cb[i] = bv[i - 2048];
  else if (i < 4096) cb[i] = bck[i - 3072];
  else if (i < 5120) cb[i] = bcv[i - 4096];
  else if (i < 6144) cb[i] = bcq[i - 5120] * 0.03125f;
  else cb[i] = 0.f;  // zeros for the P-GEMM bias
}

// -------- fused FFN bias: cb2[n] = sum_h b1[h]*W2[h][n] + b2[n] -------------
// wt9[n][h] = W2[h][n] (contiguous in h). grid 4 x 256.
__global__ __launch_bounds__(256) void bias_fuse_kernel(
    const bf16_t* __restrict__ wt9, const float* __restrict__ b1,
    const float* __restrict__ b2, float* __restrict__ cb2) {
  int n = blockIdx.x * 256 + threadIdx.x;
  const bf16_t* row = wt9 + (size_t)n * 1024;
  float acc = 0.f;
#pragma unroll 4
  for (int h = 0; h < 1024; h += 8) {
    bf16x8 v = *(const bf16x8*)(row + h);
    float4 ba = *(const float4*)(b1 + h);
    float4 bb = *(const float4*)(b1 + h + 4);
    acc += ba.x*(float)v[0] + ba.y*(float)v[1] + ba.z*(float)v[2] + ba.w*(float)v[3]
         + bb.x*(float)v[4] + bb.y*(float)v[5] + bb.z*(float)v[6] + bb.w*(float)v[7];
  }
  cb2[n] = acc + b2[n];
}

// ---------------- GEMM m97-style: C[M,ldC] = A[M,1024]bf16 @ Bt[N,1024]^T ----
// 128xBN tile, BK=64, 4 waves, global_load_lds(16B), XOR-swizzled LDS.
// Epilogue: + bias[col] (+ res) -> bf16; TRANS_OUT writes C^T (ldC = M).
template <int BN, bool HAS_RES, bool TRANS_OUT>
__global__ __launch_bounds__(256) void gemm_bf16(
    const bf16_t* __restrict__ A, const bf16_t* __restrict__ Bt,
    const float* __restrict__ bias, const bf16_t* __restrict__ res,
    bf16_t* __restrict__ C, int ldC) {
  constexpr int MI = (BN == 128) ? 4 : 2;
  constexpr int NI = 4;
  __shared__ bf16_t As[128 * 64];
  __shared__ bf16_t Bs[BN * 64];
  int tid = threadIdx.x;
  int w = tid >> 6, lane = tid & 63;
  int fm = lane & 15, fq = lane >> 4;
  int bm = blockIdx.y * 128, bn = blockIdx.x * BN;
  int wm = (BN == 128) ? (w >> 1) * 64 : w * 32;
  int wn = (BN == 128) ? (w & 1) * 64 : 0;
  f32x4 acc[MI][NI] = {};
  for (int kt = 0; kt < 1024; kt += 64) {
#pragma unroll
    for (int i = 0; i < 4; i++) {  // A: 128 rows x 8 chunks
      int c = i * 256 + tid;
      int row = c >> 3, skg = (c & 7) ^ (row & 7);
      async_copy16(A + (size_t)(bm + row) * 1024 + kt + skg * 8, &As[c * 8]);
    }
#pragma unroll
    for (int i = 0; i < BN / 32; i++) {  // B: BN rows x 8 chunks
      int c = i * 256 + tid;
      int row = c >> 3, skg = (c & 7) ^ (row & 7);
      async_copy16(Bt + (size_t)(bn + row) * 1024 + kt + skg * 8, &Bs[c * 8]);
    }
    __syncthreads();  // drains vmcnt(0): copies visible
#pragma unroll
    for (int ks = 0; ks < 2; ks++) {
      bf16x8 af[MI], bfr[NI];
      int kg = ks * 4 + fq;
#pragma unroll
      for (int mi = 0; mi < MI; mi++) {
        int row = wm + mi * 16 + fm;
        af[mi] = *(const bf16x8*)&As[row * 64 + ((kg ^ (row & 7)) * 8)];
      }
#pragma unroll
      for (int ni = 0; ni < NI; ni++) {
        int row = wn + ni * 16 + fm;
        bfr[ni] = *(const bf16x8*)&Bs[row * 64 + ((kg ^ (row & 7)) * 8)];
      }
#pragma unroll
      for (int mi = 0; mi < MI; mi++)
#pragma unroll
        for (int ni = 0; ni < NI; ni++)
          acc[mi][ni] = __builtin_amdgcn_mfma_f32_16x16x32_bf16(
              af[mi], bfr[ni], acc[mi][ni], 0, 0, 0);
    }
    __syncthreads();  // protect LDS reuse
  }
#pragma unroll
  for (int mi = 0; mi < MI; mi++) {
#pragma unroll
    for (int ni = 0; ni < NI; ni++) {
      int col = bn + wn + ni * 16 + fm;
      float bv = bias[col];
      if (TRANS_OUT) {
        int rowb = bm + wm + mi * 16 + fq * 4;
        bf16x4 w4;
#pragma unroll
        for (int r = 0; r < 4; r++) w4[r] = (bf16_t)(acc[mi][ni][r] + bv);
        *(bf16x4*)&C[(size_t)col * ldC + rowb] = w4;  // C^T: ldC = M
      } else {
#pragma unroll
        for (int r = 0; r < 4; r++) {
          int row = bm + wm + mi * 16 + fq * 4 + r;  // C/D map (m89/m91)
          float v = acc[mi][ni][r] + bv;
          if (HAS_RES) v += (float)res[(size_t)row * ldC + col];
          C[(size_t)row * ldC + col] = (bf16_t)v;
        }
      }
    }
  }
}

// ---------------- merged cq / ck / cv projections, m97 128x128 tiles --------
// region = blockIdx.x>>3: 0 -> cq = t1n@Wcq, 1 -> K = hb@Wck (row-major),
// 2 -> V^T = (hb@Wcv)^T (ldC=4096). wt[4..6] contiguous at wt4. grid (24,32).
__global__ __launch_bounds__(256) void gemm_cqkv(
    const bf16_t* __restrict__ t1n, const bf16_t* __restrict__ hb,
    const bf16_t* __restrict__ wt4, const float* __restrict__ cb,
    bf16_t* __restrict__ cq, bf16_t* __restrict__ kbuf,
    bf16_t* __restrict__ vt) {
  constexpr int MI = 4, NI = 4;
  __shared__ bf16_t As[128 * 64];
  __shared__ bf16_t Bs[128 * 64];
  int region = blockIdx.x >> 3;
  int bn = (blockIdx.x & 7) * 128;
  const bf16_t* A = (region == 0) ? t1n : hb;
  const bf16_t* Bt = wt4 + (size_t)region * 1048576;
  int boff = (region == 0) ? 5120 : ((region == 1) ? 3072 : 4096);
  int tid = threadIdx.x;
  int w = tid >> 6, lane = tid & 63;
  int fm = lane & 15, fq = lane >> 4;
  int bm = blockIdx.y * 128;
  int wm = (w >> 1) * 64, wn = (w & 1) * 64;
  f32x4 acc[MI][NI] = {};
  for (int kt = 0; kt < 1024; kt += 64) {
#pragma unroll
    for (int i = 0; i < 4; i++) {
      int c = i * 256 + tid;
      int row = c >> 3, skg = (c & 7) ^ (row & 7);
      async_copy16(A + (size_t)(bm + row) * 1024 + kt + skg * 8, &As[c * 8]);
    }
#pragma unroll
    for (int i = 0; i < 4; i++) {
      int c = i * 256 + tid;
      int row = c >> 3, skg = (c & 7) ^ (row & 7);
      async_copy16(Bt + (size_t)(bn + row) * 1024 + kt + skg * 8, &Bs[c * 8]);
    }
    __syncthreads();
#pragma unroll
    for (int ks = 0; ks < 2; ks++) {
      bf16x8 af[MI], bfr[NI];
      int kg = ks * 4 + fq;
#pragma unroll
      for (int mi = 0; mi < MI; mi++) {
        int row = wm + mi * 16 + fm;
        af[mi] = *(const bf16x8*)&As[row * 64 + ((kg ^ (row & 7)) * 8)];
      }
#pragma unroll
      for (int ni = 0; ni < NI; ni++) {
        int row = wn + ni * 16 + fm;
        bfr[ni] = *(const bf16x8*)&Bs[row * 64 + ((kg ^ (row & 7)) * 8)];
      }
#pragma unroll
      for (int mi = 0; mi < MI; mi++)
#pragma unroll
        for (int ni = 0; ni < NI; ni++)
          acc[mi][ni] = __builtin_amdgcn_mfma_f32_16x16x32_bf16(
              af[mi], bfr[ni], acc[mi][ni], 0, 0, 0);
    }
    __syncthreads();
  }
#pragma unroll
  for (int mi = 0; mi < MI; mi++) {
#pragma unroll
    for (int ni = 0; ni < NI; ni++) {
      int col = bn + wn + ni * 16 + fm;
      float bv = cb[boff + col];
      if (region == 2) {  // V^T
        int rowb = bm + wm + mi * 16 + fq * 4;
        bf16x4 w4;
#pragma unroll
        for (int r = 0; r < 4; r++) w4[r] = (bf16_t)(acc[mi][ni][r] + bv);
        *(bf16x4*)&vt[(size_t)col * 4096 + rowb] = w4;
      } else {
        bf16_t* C = (region == 0) ? cq : kbuf;
#pragma unroll
        for (int r = 0; r < 4; r++) {
          int row = bm + wm + mi * 16 + fq * 4 + r;
          C[(size_t)row * 1024 + col] = (bf16_t)(acc[mi][ni][r] + bv);
        }
      }
    }
  }
}

// ---------------- self-attn core: causal softmax over C=64 channels ---------
// QKV packed [4096][3072] bf16 (Q|K|V), O [4096][1024] bf16. Q pre-scaled 1/8.
// K,V staged to LDS as f32 pairs; uniform-address ds_read broadcasts.
// 4 independent accumulation chains so exp (trans pipe) overlaps VALU issue.
__global__ __launch_bounds__(256) void self_attn_kernel(
    const bf16_t* __restrict__ QKV, bf16_t* __restrict__ O) {
  __shared__ float2 kv[4][64];
  int tid = threadIdx.x;
  int wu = tid >> 6, lane = tid & 63;
  int unit = blockIdx.x * 4 + wu;  // m*16 + h
  int m = unit >> 4, h = unit & 15;
  size_t iq = (size_t)m * 3072 + h * 64 + lane;
  float q = (float)QKV[iq] * 1.44269504089f;
  float kk = (float)QKV[iq + 1024];
  float vv = (float)QKV[iq + 2048];
  kv[wu][lane] = make_float2(kk, vv);
  __syncthreads();
  const float2* kvp = kv[wu];
  float l0 = 0.f, l1 = 0.f, l2 = 0.f, l3 = 0.f;
  float o0 = 0.f, o1 = 0.f, o2 = 0.f, o3 = 0.f;
#pragma unroll
  for (int j = 0; j < 64; j += 4) {
    float2 a = kvp[j];
    float2 b = kvp[j + 1];
    float2 c = kvp[j + 2];
    float2 d = kvp[j + 3];
    float e0 = fast_exp2(q * a.x);
    float e1 = fast_exp2(q * b.x);
    float e2 = fast_exp2(q * c.x);
    float e3 = fast_exp2(q * d.x);
    e0 = (j     <= lane) ? e0 : 0.f;
    e1 = (j + 1 <= lane) ? e1 : 0.f;
    e2 = (j + 2 <= lane) ? e2 : 0.f;
    e3 = (j + 3 <= lane) ? e3 : 0.f;
    l0 += e0; o0 = fmaf(e0, a.y, o0);
    l1 += e1; o1 = fmaf(e1, b.y, o1);
    l2 += e2; o2 = fmaf(e2, c.y, o2);
    l3 += e3; o3 = fmaf(e3, d.y, o3);
  }
  float l = (l0 + l1) + (l2 + l3);
  float o = (o0 + o1) + (o2 + o3);
  O[(size_t)m * 1024 + h * 64 + lane] = (bf16_t)(o / l);
}

// ---------------- cross-attn, MFMA flash ------------------------------------
// Per block: one (b,h), 64 q-rows; 4 waves x 16 q-rows. K-tile = 64.
// S^T = K.Q^T  (A=K rows from LDS, B=Q rows in regs) -> stats per q=lane&15.
// O^T = Vt.P^T (A=Vt rows from LDS, B=P^T via shfl+select transform).
// Q prescaled 1/32. Kb [4096][1024]; Vt [1024][4096]; O [4096][1024].
__global__ __launch_bounds__(256) void cross_attn_mfma(
    const bf16_t* __restrict__ Q, const bf16_t* __restrict__ Kb,
    const bf16_t* __restrict__ Vt, bf16_t* __restrict__ O) {
  __shared__ bf16_t Ks[64 * 64];
  __shared__ bf16_t Vs[64 * 64];
  int tid = threadIdx.x;
  int w = tid >> 6, lane = tid & 63;
  int fm = lane & 15, fq = lane >> 4;
  int bh = blockIdx.x;
  int b = bh >> 4, h = bh & 15;
  int q0 = blockIdx.y * 64 + w * 16;
  const bf16_t* Qp = Q + (size_t)(b * 512 + q0 + fm) * 1024 + h * 64 + fq * 8;
  bf16x8 qf0 = *(const bf16x8*)Qp;
  bf16x8 qf1 = *(const bf16x8*)(Qp + 32);
  f32x4 o[4] = {};  // O^T tiles ct: lane holds O^T[c=ct*16+fq*4+r][q=fm]
  float mx = -1e30f, l = 0.f;
  for (int k0 = 0; k0 < 512; k0 += 64) {
    __syncthreads();  // previous tile's LDS reads complete
#pragma unroll
    for (int i = 0; i < 2; i++) {  // 64 rows x 8 chunks, XOR swizzle
      int c = i * 256 + tid;
      int row = c >> 3, kg = (c & 7) ^ (row & 7);
      async_copy16(Kb + (size_t)(b * 512 + k0 + row) * 1024 + h * 64 + kg * 8,
                   &Ks[c * 8]);
      async_copy16(Vt + (size_t)(h * 64 + row) * 4096 + b * 512 + k0 + kg * 8,
                   &Vs[c * 8]);
    }
    __syncthreads();  // drain global_load_lds
    // S^T tiles mt: lane holds S^T[k=mt*16+fq*4+r][q=fm]
    f32x4 s[4] = {};
#pragma unroll
    for (int mt = 0; mt < 4; mt++) {
      int row = mt * 16 + fm;
#pragma unroll
      for (int f = 0; f < 2; f++) {
        int kg = f * 4 + fq;
        bf16x8 kf = *(const bf16x8*)&Ks[row * 64 + ((kg ^ (row & 7)) * 8)];
        s[mt] = __builtin_amdgcn_mfma_f32_16x16x32_bf16(
            kf, (f ? qf1 : qf0), s[mt], 0, 0, 0);
      }
    }
    // online softmax (stats per q=fm, replicated across quads)
    float smax = -1e30f;
#pragma unroll
    for (int mt = 0; mt < 4; mt++)
#pragma unroll
      for (int r = 0; r < 4; r++) smax = fmaxf(smax, s[mt][r]);
    smax = fmaxf(smax, __shfl_xor(smax, 16, 64));
    smax = fmaxf(smax, __shfl_xor(smax, 32, 64));
    float nm = fmaxf(mx, smax);
    float corr = __expf(mx - nm);
    float ladd = 0.f;
    unsigned pk0[4], pk1[4];
#pragma unroll
    for (int mt = 0; mt < 4; mt++) {
      float p0 = __expf(s[mt][0] - nm);
      float p1 = __expf(s[mt][1] - nm);
      float p2 = __expf(s[mt][2] - nm);
      float p3 = __expf(s[mt][3] - nm);
      ladd += (p0 + p1) + (p2 + p3);
      pk0[mt] = pack_bf16(p0, p1);
      pk1[mt] = pack_bf16(p2, p3);
    }
    ladd += __shfl_xor(ladd, 16, 64);
    ladd += __shfl_xor(ladd, 32, 64);
    l = l * corr + ladd;
#pragma unroll
    for (int ct = 0; ct < 4; ct++)
#pragma unroll
      for (int r = 0; r < 4; r++) o[ct][r] *= corr;
    union U { unsigned u[4]; bf16x8 v; } pf[2];
    int sl0 = ((fq & 1) * 2) * 16 + fm;
    int sl1 = sl0 + 16;
    bool hi = fq >= 2;
#pragma unroll
    for (int f = 0; f < 2; f++) {
      unsigned a0 = (unsigned)__shfl((int)pk0[f * 2],     sl0, 64);
      unsigned b0 = (unsigned)__shfl((int)pk0[f * 2 + 1], sl0, 64);
      unsigned a1 = (unsigned)__shfl((int)pk1[f * 2],     sl0, 64);
      unsigned b1 = (unsigned)__shfl((int)pk1[f * 2 + 1], sl0, 64);
      unsigned a2 = (unsigned)__shfl((int)pk0[f * 2],     sl1, 64);
      unsigned b2 = (unsigned)__shfl((int)pk0[f * 2 + 1], sl1, 64);
      unsigned a3 = (unsigned)__shfl((int)pk1[f * 2],     sl1, 64);
      unsigned b3 = (unsigned)__shfl((int)pk1[f * 2 + 1], sl1, 64);
      pf[f].u[0] = hi ? b0 : a0;
      pf[f].u[1] = hi ? b1 : a1;
      pf[f].u[2] = hi ? b2 : a2;
      pf[f].u[3] = hi ? b3 : a3;
    }
#pragma unroll
    for (int ct = 0; ct < 4; ct++) {
      int row = ct * 16 + fm;
#pragma unroll
      for (int f = 0; f < 2; f++) {
        int kg = f * 4 + fq;
        bf16x8 vf = *(const bf16x8*)&Vs[row * 64 + ((kg ^ (row & 7)) * 8)];
        o[ct] = __builtin_amdgcn_mfma_f32_16x16x32_bf16(vf, pf[f].v, o[ct], 0, 0, 0);
      }
    }
    mx = nm;
  }
  float inv = 1.f / l;
  bf16_t* Op = O + (size_t)(b * 512 + q0 + fm) * 1024 + h * 64 + fq * 4;
#pragma unroll
  for (int ct = 0; ct < 4; ct++) {
    bf16x4 w4;
    w4[0] = (bf16_t)(o[ct][0] * inv);
    w4[1] = (bf16_t)(o[ct][1] * inv);
    w4[2] = (bf16_t)(o[ct][2] * inv);
    w4[3] = (bf16_t)(o[ct][3] * inv);
    *(bf16x4*)(Op + ct * 16) = w4;
  }
}

// ---------------- LayerNorm D=1024, bf16 in, OutT out -----------------------
template <typename OutT>
__global__ __launch_bounds__(256) void ln_kernel(
    const bf16_t* __restrict__ X, const float* __restrict__ gamma,
    const float* __restrict__ beta, OutT* __restrict__ Y) {
  __shared__ float red[8];
  int row = blockIdx.x;
  int tid = threadIdx.x;
  bf16x4 x4 = *(const bf16x4*)(X + (size_t)row * 1024 + tid * 4);
  float4 v = {(float)x4[0], (float)x4[1], (float)x4[2], (float)x4[3]};
  float s = (v.x + v.y) + (v.z + v.w);
  float ss = fmaf(v.x, v.x, fmaf(v.y, v.y, fmaf(v.z, v.z, v.w * v.w)));
#pragma unroll
  for (int off = 32; off > 0; off >>= 1) {
    s  += __shfl_down(s, off, 64);
    ss += __shfl_down(ss, off, 64);
  }
  if ((tid & 63) == 0) { red[tid >> 6] = s; red[4 + (tid >> 6)] = ss; }
  __syncthreads();
  float S  = (red[0] + red[1]) + (red[2] + red[3]);
  float SS = (red[4] + red[5]) + (red[6] + red[7]);
  float mu = S * (1.f / 1024.f);
  float var = SS * (1.f / 1024.f) - mu * mu;
  float inv = rsqrtf(var + 1e-5f);
  float4 g = *(const float4*)(gamma + tid * 4);
  float4 b = *(const float4*)(beta + tid * 4);
  float r0 = (v.x - mu) * inv * g.x + b.x;
  float r1 = (v.y - mu) * inv * g.y + b.y;
  float r2 = (v.z - mu) * inv * g.z + b.z;
  float r3 = (v.w - mu) * inv * g.w + b.w;
  OutT* yp = Y + (size_t)row * 1024 + tid * 4;
  yp[0] = (OutT)r0; yp[1] = (OutT)r1; yp[2] = (OutT)r2; yp[3] = (OutT)r3;
}

extern "C" void kernel_launch(void* const* d_in, const int* in_sizes, int n_in,
                              void* d_out, int out_size, void* d_ws, size_t ws_size,
                              hipStream_t stream) {
  (void)in_sizes; (void)n_in; (void)out_size; (void)ws_size;
  const float* x  = (const float*)d_in[0];
  const float* hh = (const float*)d_in[1];
  SrcPtrs sp;
  sp.p[0] = (const float*)d_in[2];  sp.p[1] = (const float*)d_in[4];
  sp.p[2] = (const float*)d_in[6];  sp.p[3] = (const float*)d_in[8];
  sp.p[4] = (const float*)d_in[10]; sp.p[5] = (const float*)d_in[12];
  sp.p[6] = (const float*)d_in[14]; sp.p[7] = (const float*)d_in[16];
  sp.p[8] = (const float*)d_in[20]; sp.p[9] = (const float*)d_in[22];
  const float* W1f = (const float*)d_in[20];
  const float* bq  = (const float*)d_in[3];
  const float* bk  = (const float*)d_in[5];
  const float* bv  = (const float*)d_in[7];
  const float* bo  = (const float*)d_in[9];
  const float* bck = (const float*)d_in[13];
  const float* bcv = (const float*)d_in[15];
  const float* bcq = (const float*)d_in[11];
  const float* bco = (const float*)d_in[17];
  const float* gamma = (const float*)d_in[18];
  const float* beta  = (const float*)d_in[19];
  const float* b1  = (const float*)d_in[21];
  const float* b2  = (const float*)d_in[23];
  float* out = (float*)d_out;
  char* ws = (char*)d_ws;
  const size_t MB = 1048576;

  bf16_t* wt[10];
  for (int i = 0; i < 10; i++) wt[i] = (bf16_t*)(ws + (size_t)i * 2 * MB);
  float* cb      = (float*)(ws + 20 * MB);        // [q|k|v|ck|cv|cq|0] x1024
  float* cb2     = (float*)(ws + 20 * MB + 32768);// fused FFN bias [1024]
  bf16_t* xb     = (bf16_t*)(ws + 21 * MB);  // 8MB; reused as t1n later
  bf16_t* hb     = (bf16_t*)(ws + 29 * MB);  // 8MB; reused as t2n later
  bf16_t* w1bf   = (bf16_t*)(ws + 37 * MB);  // 2MB; dead after P-GEMM
  bf16_t* qkv    = (bf16_t*)(ws + 37 * MB);  // 24MB (overwrites w1bf; ok)
  bf16_t* kbuf   = (bf16_t*)(ws + 37 * MB);  // 8MB  (reuse qkv)
  bf16_t* vtbuf  = (bf16_t*)(ws + 45 * MB);  // 8MB  [1024][4096]
  bf16_t* cqbuf  = (bf16_t*)(ws + 61 * MB);  // 8MB
  bf16_t* attn   = (bf16_t*)(ws + 69 * MB);  // 8MB
  bf16_t* g4     = (bf16_t*)(ws + 77 * MB);  // 8MB; reused as f2out
  bf16_t* ptbuf  = (bf16_t*)(ws + 85 * MB);  // 2MB  P^T = (W1@W2)^T as Bt
  bf16_t* t1n    = xb;
  bf16_t* t2n    = hb;
  bf16_t* f2out  = g4;

  // prep: casts, weight transposes, biases, FFN weight collapse P = W1@W2
  cast3_bf16_kernel<<<4608, 256, 0, stream>>>(x, hh, W1f, xb);
  transpose_cast_all<<<dim3(32, 32, 10), dim3(32, 8), 0, stream>>>(sp, (bf16_t*)ws);
  prep_bias_kernel<<<28, 256, 0, stream>>>(bq, bk, bv, bck, bcv, bcq, cb);
  bias_fuse_kernel<<<4, 256, 0, stream>>>(wt[9], b1, b2, cb2);
  // Pt[n][k] = sum_h W2^T[n][h] * W1[k][h]  (A=wt9 row-major, Bt=w1bf)
  gemm_bf16<64, false, false><<<dim3(16, 8), 256, 0, stream>>>(wt[9], w1bf, cb + 6144, nullptr, ptbuf, 1024);

  // self-attn block
  gemm_bf16<128, false, false><<<dim3(24, 32), 256, 0, stream>>>(xb, wt[0], cb, nullptr, qkv, 3072);
  self_attn_kernel<<<16384, 256, 0, stream>>>(qkv, attn);
  gemm_bf16<64, true, false><<<dim3(16, 32), 256, 0, stream>>>(attn, wt[3], bo, xb, g4, 1024);
  ln_kernel<bf16_t><<<4096, 256, 0, stream>>>(g4, gamma, beta, t1n);
  // cross-attn block (t1n == xb: written after xb's last read above)
  gemm_cqkv<<<dim3(24, 32), 256, 0, stream>>>(t1n, hb, wt[4], cb, cqbuf, kbuf, vtbuf);
  cross_attn_mfma<<<dim3(128, 8), 256, 0, stream>>>(cqbuf, kbuf, vtbuf, attn);
  gemm_bf16<64, true, false><<<dim3(16, 32), 256, 0, stream>>>(attn, wt[7], bco, t1n, g4, 1024);
  ln_kernel<bf16_t><<<4096, 256, 0, stream>>>(g4, gamma, beta, t2n);
  // FFN collapsed: out = t2n @ P + (b1@W2 + b2) + t2n
  gemm_bf16<64, true, false><<<dim3(16, 32), 256, 0, stream>>>(t2n, ptbuf, cb2, t2n, f2out, 1024);
  ln_kernel<float><<<4096, 256, 0, stream>>>(f2out, gamma, beta, out);
}

// Round 8
// 401.482 us; speedup vs baseline: 1.0214x; 1.0214x over previous
//
#include <hip/hip_runtime.h>

typedef __bf16 bf16_t;
typedef bf16_t bf16x8 __attribute__((ext_vector_type(8)));
typedef bf16_t bf16x4 __attribute__((ext_vector_type(4)));
typedef float f32x4 __attribute__((ext_vector_type(4)));

// async global->LDS 16B per lane. LDS dest = wave-uniform base + lane*16
// (m97/m104): per-lane pointers must be linear in lane index.
__device__ __forceinline__ void async_copy16(const void* g, void* l) {
  __builtin_amdgcn_global_load_lds(
      (const __attribute__((address_space(1))) unsigned int*)(unsigned long long)g,
      (__attribute__((address_space(3))) unsigned int*)(unsigned int)(unsigned long long)l,
      16, 0, 0);
}

__device__ __forceinline__ float fast_exp2(float x) {
#if __has_builtin(__builtin_amdgcn_exp2f)
  return __builtin_amdgcn_exp2f(x);
#else
  return exp2f(x);
#endif
}

__device__ __forceinline__ unsigned pack_bf16(float x, float y) {
  bf16_t lo = (bf16_t)x, hi = (bf16_t)y;
  unsigned short ul, uh;
  __builtin_memcpy(&ul, &lo, 2);
  __builtin_memcpy(&uh, &hi, 2);
  return (unsigned)ul | ((unsigned)uh << 16);
}

// ------- cast x,h -> xb|hb (contiguous) and W1 -> w1bf (separate dst) -------
__global__ __launch_bounds__(256) void cast3_bf16_kernel(
    const float* __restrict__ a, const float* __restrict__ b,
    const float* __restrict__ w1, bf16_t* __restrict__ dst1,
    bf16_t* __restrict__ dstw) {
  int i = (blockIdx.x * 256 + threadIdx.x) * 8;  // [0, 9M)
  const float* s;
  bf16_t* d;
  if (i < 4194304) { s = a + i; d = dst1 + i; }
  else if (i < 8388608) { s = b + i - 4194304; d = dst1 + i; }
  else { s = w1 + i - 8388608; d = dstw + (i - 8388608); }
  float4 u = *(const float4*)s;
  float4 v = *(const float4*)(s + 4);
  bf16x8 o;
  o[0]=(bf16_t)u.x; o[1]=(bf16_t)u.y; o[2]=(bf16_t)u.z; o[3]=(bf16_t)u.w;
  o[4]=(bf16_t)v.x; o[5]=(bf16_t)v.y; o[6]=(bf16_t)v.z; o[7]=(bf16_t)v.w;
  *(bf16x8*)d = o;
}

// ---------------- all-weights transpose+cast+scale (grid.z = weight idx) ----
struct SrcPtrs { const float* p[10]; };
__global__ __launch_bounds__(256) void transpose_cast_all(
    SrcPtrs srcs, bf16_t* __restrict__ dstbase) {
  __shared__ float tile[32][33];
  int z = blockIdx.z;
  const float* src = srcs.p[z];
  bf16_t* dst = dstbase + (size_t)z * 1048576;
  float scale = (z == 0) ? 0.125f : ((z == 4) ? 0.03125f : 1.f);
  int bx = blockIdx.x * 32;  // n base
  int by = blockIdx.y * 32;  // k base
  int tx = threadIdx.x, ty = threadIdx.y;
#pragma unroll
  for (int i = 0; i < 32; i += 8)
    tile[ty + i][tx] = src[(size_t)(by + ty + i) * 1024 + bx + tx];
  __syncthreads();
#pragma unroll
  for (int i = 0; i < 32; i += 8)
    dst[(size_t)(bx + ty + i) * 1024 + by + tx] = (bf16_t)(tile[tx][ty + i] * scale);
}

// --- bias concat [q|k|v|ck|cv|cq|zeros] x1024 + fused FFN bias (blk 28-31) --
__global__ __launch_bounds__(256) void prep_bias_kernel(
    const float* __restrict__ bq, const float* __restrict__ bk,
    const float* __restrict__ bv, const float* __restrict__ bck,
    const float* __restrict__ bcv, const float* __restrict__ bcq,
    const bf16_t* __restrict__ wt9, const float* __restrict__ b1,
    const float* __restrict__ b2, float* __restrict__ cb,
    float* __restrict__ cb2) {
  int bid = blockIdx.x;
  if (bid < 28) {
    int i = bid * 256 + threadIdx.x;
    if (i < 1024) cb[i] = bq[i] * 0.125f;
    else if (i < 2048) cb[i] = bk[i - 1024];
    else if (i < 3072) cb[i] = bv[i - 2048];
    else if (i < 4096) cb[i] = bck[i - 3072];
    else if (i < 5120) cb[i] = bcv[i - 4096];
    else if (i < 6144) cb[i] = bcq[i - 5120] * 0.03125f;
    else cb[i] = 0.f;  // zeros for the P-GEMM bias
  } else {
    // cb2[n] = sum_h b1[h]*W2[h][n] + b2[n];  wt9[n][h] = W2[h][n]
    int n = (bid - 28) * 256 + threadIdx.x;
    const bf16_t* row = wt9 + (size_t)n * 1024;
    float acc = 0.f;
#pragma unroll 4
    for (int h = 0; h < 1024; h += 8) {
      bf16x8 v = *(const bf16x8*)(row + h);
      float4 ba = *(const float4*)(b1 + h);
      float4 bb = *(const float4*)(b1 + h + 4);
      acc += ba.x*(float)v[0] + ba.y*(float)v[1] + ba.z*(float)v[2] + ba.w*(float)v[3]
           + bb.x*(float)v[4] + bb.y*(float)v[5] + bb.z*(float)v[6] + bb.w*(float)v[7];
    }
    cb2[n] = acc + b2[n];
  }
}

// ---------------- shared GEMM core: C[*,ldC] = A[*,1024] @ Bt[*,1024]^T -----
// 128xBN tile, BK=64, 4 waves, global_load_lds(16B), XOR-swizzled LDS.
// Epilogue: + bias[bn+local] (+ res) -> bf16; TRANS_OUT writes C^T (ldC = M).
template <int BN, int MI, bool HAS_RES, bool TRANS_OUT>
__device__ __forceinline__ void gemm_core(
    const bf16_t* __restrict__ A, const bf16_t* __restrict__ Bt,
    const float* __restrict__ bias, const bf16_t* __restrict__ res,
    bf16_t* __restrict__ C, int ldC, int bm, int bn,
    bf16_t* As, bf16_t* Bs) {
  constexpr int NI = 4;
  int tid = threadIdx.x;
  int w = tid >> 6, lane = tid & 63;
  int fm = lane & 15, fq = lane >> 4;
  int wm = (BN == 128) ? (w >> 1) * 64 : w * 32;
  int wn = (BN == 128) ? (w & 1) * 64 : 0;
  f32x4 acc[MI][NI] = {};
  for (int kt = 0; kt < 1024; kt += 64) {
#pragma unroll
    for (int i = 0; i < 4; i++) {  // A: 128 rows x 8 chunks
      int c = i * 256 + tid;
      int row = c >> 3, skg = (c & 7) ^ (row & 7);
      async_copy16(A + (size_t)(bm + row) * 1024 + kt + skg * 8, &As[c * 8]);
    }
#pragma unroll
    for (int i = 0; i < BN / 32; i++) {  // B: BN rows x 8 chunks
      int c = i * 256 + tid;
      int row = c >> 3, skg = (c & 7) ^ (row & 7);
      async_copy16(Bt + (size_t)(bn + row) * 1024 + kt + skg * 8, &Bs[c * 8]);
    }
    __syncthreads();  // drains vmcnt(0): copies visible
#pragma unroll
    for (int ks = 0; ks < 2; ks++) {
      bf16x8 af[MI], bfr[NI];
      int kg = ks * 4 + fq;
#pragma unroll
      for (int mi = 0; mi < MI; mi++) {
        int row = wm + mi * 16 + fm;
        af[mi] = *(const bf16x8*)&As[row * 64 + ((kg ^ (row & 7)) * 8)];
      }
#pragma unroll
      for (int ni = 0; ni < NI; ni++) {
        int row = wn + ni * 16 + fm;
        bfr[ni] = *(const bf16x8*)&Bs[row * 64 + ((kg ^ (row & 7)) * 8)];
      }
#pragma unroll
      for (int mi = 0; mi < MI; mi++)
#pragma unroll
        for (int ni = 0; ni < NI; ni++)
          acc[mi][ni] = __builtin_amdgcn_mfma_f32_16x16x32_bf16(
              af[mi], bfr[ni], acc[mi][ni], 0, 0, 0);
    }
    __syncthreads();  // protect LDS reuse
  }
#pragma unroll
  for (int mi = 0; mi < MI; mi++) {
#pragma unroll
    for (int ni = 0; ni < NI; ni++) {
      int col = bn + wn + ni * 16 + fm;
      float bv = bias[col];
      if (TRANS_OUT) {
        int rowb = bm + wm + mi * 16 + fq * 4;
        bf16x4 w4;
#pragma unroll
        for (int r = 0; r < 4; r++) w4[r] = (bf16_t)(acc[mi][ni][r] + bv);
        *(bf16x4*)&C[(size_t)col * ldC + rowb] = w4;  // C^T: ldC = M
      } else {
#pragma unroll
        for (int r = 0; r < 4; r++) {
          int row = bm + wm + mi * 16 + fq * 4 + r;  // C/D map (m89/m91)
          float v = acc[mi][ni][r] + bv;
          if (HAS_RES) v += (float)res[(size_t)row * ldC + col];
          C[(size_t)row * ldC + col] = (bf16_t)v;
        }
      }
    }
  }
}

// ---------------- standalone GEMM kernel (BN=64 used for N=1024 GEMMs) ------
template <int BN, bool HAS_RES, bool TRANS_OUT>
__global__ __launch_bounds__(256) void gemm_bf16(
    const bf16_t* __restrict__ A, const bf16_t* __restrict__ Bt,
    const float* __restrict__ bias, const bf16_t* __restrict__ res,
    bf16_t* __restrict__ C, int ldC) {
  __shared__ bf16_t As[128 * 64];
  __shared__ bf16_t Bs[BN * 64];
  gemm_core<BN, (BN == 128) ? 4 : 2, HAS_RES, TRANS_OUT>(
      A, Bt, bias, res, C, ldC, blockIdx.y * 128, blockIdx.x * BN, As, Bs);
}

// -------- merged qkv (BN=128, x<24) + FFN-collapse P-GEMM (x>=24) -----------
// qkv: C[4096][3072] = xb @ [Wq|Wk|Wv], grid.x 0..23, grid.y 0..31.
// P:   Pt[1024][1024] = wt9 @ w1bf^T (Pt[n][k] = sum_h W2[h][n] W1[k][h]),
//      128 blocks decoded from (x-24, y): rides in the same dispatch.
__global__ __launch_bounds__(256) void gemm_qkv_p(
    const bf16_t* __restrict__ xb, const bf16_t* __restrict__ wt0,
    const bf16_t* __restrict__ wt9, const bf16_t* __restrict__ w1bf,
    const float* __restrict__ cb, bf16_t* __restrict__ qkv,
    bf16_t* __restrict__ pt) {
  __shared__ bf16_t smem[2 * 128 * 64];  // 32 KB
  if (blockIdx.x < 24) {
    gemm_core<128, 4, false, false>(xb, wt0, cb, nullptr, qkv, 3072,
                                    blockIdx.y * 128, blockIdx.x * 128,
                                    smem, smem + 128 * 64);
  } else {
    int lin = (blockIdx.x - 24) * 32 + blockIdx.y;  // [0,128)
    gemm_core<64, 2, false, false>(wt9, w1bf, cb + 6144, nullptr, pt, 1024,
                                   (lin >> 4) * 128, (lin & 15) * 64,
                                   smem, smem + 128 * 64);
  }
}

// ---------------- merged cq / ck / cv projections (R6 config: BN=64) --------
// region = blockIdx.x>>4: 0 -> cq = t1n@Wcq, 1 -> K = hb@Wck (row-major),
// 2 -> V^T = (hb@Wcv)^T (ldC=4096). wt[4..6] contiguous at wt4. grid (48,32).
__global__ __launch_bounds__(256) void gemm_cqkv(
    const bf16_t* __restrict__ t1n, const bf16_t* __restrict__ hb,
    const bf16_t* __restrict__ wt4, const float* __restrict__ cb,
    bf16_t* __restrict__ cq, bf16_t* __restrict__ kbuf,
    bf16_t* __restrict__ vt) {
  __shared__ bf16_t As[128 * 64];
  __shared__ bf16_t Bs[64 * 64];
  int region = blockIdx.x >> 4;
  int bn = (blockIdx.x & 15) * 64;
  int bm = blockIdx.y * 128;
  const bf16_t* Bt = wt4 + (size_t)region * 1048576;
  if (region == 2) {
    gemm_core<64, 2, false, true>(hb, Bt, cb + 4096, nullptr, vt, 4096,
                                  bm, bn, As, Bs);
  } else if (region == 1) {
    gemm_core<64, 2, false, false>(hb, Bt, cb + 3072, nullptr, kbuf, 1024,
                                   bm, bn, As, Bs);
  } else {
    gemm_core<64, 2, false, false>(t1n, Bt, cb + 5120, nullptr, cq, 1024,
                                   bm, bn, As, Bs);
  }
}

// ---------------- self-attn core: causal softmax over C=64 channels ---------
// QKV packed [4096][3072] bf16 (Q|K|V), O [4096][1024] bf16. Q pre-scaled 1/8.
// K,V staged once to LDS as f32 pairs; uniform-address ds_read broadcasts
// (conflict-free, prefetchable). 2-way split accumulators (R6-verified best).
__global__ __launch_bounds__(256) void self_attn_kernel(
    const bf16_t* __restrict__ QKV, bf16_t* __restrict__ O) {
  __shared__ float2 kv[4][64];
  int tid = threadIdx.x;
  int wu = tid >> 6, lane = tid & 63;
  int unit = blockIdx.x * 4 + wu;  // m*16 + h
  int m = unit >> 4, h = unit & 15;
  size_t iq = (size_t)m * 3072 + h * 64 + lane;
  float q = (float)QKV[iq] * 1.44269504089f;
  float kk = (float)QKV[iq + 1024];
  float vv = (float)QKV[iq + 2048];
  kv[wu][lane] = make_float2(kk, vv);
  __syncthreads();
  const float2* kvp = kv[wu];
  float l0 = 0.f, l1 = 0.f, o0 = 0.f, o1 = 0.f;
#pragma unroll
  for (int j = 0; j < 64; j += 2) {
    float2 a = kvp[j];      // uniform-address LDS broadcast
    float2 b = kvp[j + 1];
    float e0 = fast_exp2(q * a.x);
    float e1 = fast_exp2(q * b.x);
    e0 = (j <= lane) ? e0 : 0.f;
    e1 = (j + 1 <= lane) ? e1 : 0.f;
    l0 += e0; o0 = fmaf(e0, a.y, o0);
    l1 += e1; o1 = fmaf(e1, b.y, o1);
  }
  float l = l0 + l1, o = o0 + o1;
  O[(size_t)m * 1024 + h * 64 + lane] = (bf16_t)(o / l);
}

// ---------------- cross-attn, MFMA flash ------------------------------------
// Per block: one (b,h), 64 q-rows; 4 waves x 16 q-rows. K-tile = 64.
// S^T = K.Q^T  (A=K rows from LDS, B=Q rows in regs) -> stats per q=lane&15.
// O^T = Vt.P^T (A=Vt rows from LDS, B=P^T via shfl+select transform).
// Q prescaled 1/32. Kb [4096][1024]; Vt [1024][4096]; O [4096][1024].
__global__ __launch_bounds__(256) void cross_attn_mfma(
    const bf16_t* __restrict__ Q, const bf16_t* __restrict__ Kb,
    const bf16_t* __restrict__ Vt, bf16_t* __restrict__ O) {
  __shared__ bf16_t Ks[64 * 64];
  __shared__ bf16_t Vs[64 * 64];
  int tid = threadIdx.x;
  int w = tid >> 6, lane = tid & 63;
  int fm = lane & 15, fq = lane >> 4;
  int bh = blockIdx.x;
  int b = bh >> 4, h = bh & 15;
  int q0 = blockIdx.y * 64 + w * 16;
  const bf16_t* Qp = Q + (size_t)(b * 512 + q0 + fm) * 1024 + h * 64 + fq * 8;
  bf16x8 qf0 = *(const bf16x8*)Qp;
  bf16x8 qf1 = *(const bf16x8*)(Qp + 32);
  f32x4 o[4] = {};  // O^T tiles ct: lane holds O^T[c=ct*16+fq*4+r][q=fm]
  float mx = -1e30f, l = 0.f;
  for (int k0 = 0; k0 < 512; k0 += 64) {
    __syncthreads();  // previous tile's LDS reads complete
#pragma unroll
    for (int i = 0; i < 2; i++) {  // 64 rows x 8 chunks, XOR swizzle
      int c = i * 256 + tid;
      int row = c >> 3, kg = (c & 7) ^ (row & 7);
      async_copy16(Kb + (size_t)(b * 512 + k0 + row) * 1024 + h * 64 + kg * 8,
                   &Ks[c * 8]);
      async_copy16(Vt + (size_t)(h * 64 + row) * 4096 + b * 512 + k0 + kg * 8,
                   &Vs[c * 8]);
    }
    __syncthreads();  // drain global_load_lds
    // S^T tiles mt: lane holds S^T[k=mt*16+fq*4+r][q=fm]
    f32x4 s[4] = {};
#pragma unroll
    for (int mt = 0; mt < 4; mt++) {
      int row = mt * 16 + fm;
#pragma unroll
      for (int f = 0; f < 2; f++) {
        int kg = f * 4 + fq;
        bf16x8 kf = *(const bf16x8*)&Ks[row * 64 + ((kg ^ (row & 7)) * 8)];
        s[mt] = __builtin_amdgcn_mfma_f32_16x16x32_bf16(
            kf, (f ? qf1 : qf0), s[mt], 0, 0, 0);
      }
    }
    // online softmax (stats per q=fm, replicated across quads)
    float smax = -1e30f;
#pragma unroll
    for (int mt = 0; mt < 4; mt++)
#pragma unroll
      for (int r = 0; r < 4; r++) smax = fmaxf(smax, s[mt][r]);
    smax = fmaxf(smax, __shfl_xor(smax, 16, 64));
    smax = fmaxf(smax, __shfl_xor(smax, 32, 64));
    float nm = fmaxf(mx, smax);
    float corr = __expf(mx - nm);
    float ladd = 0.f;
    unsigned pk0[4], pk1[4];
#pragma unroll
    for (int mt = 0; mt < 4; mt++) {
      float p0 = __expf(s[mt][0] - nm);
      float p1 = __expf(s[mt][1] - nm);
      float p2 = __expf(s[mt][2] - nm);
      float p3 = __expf(s[mt][3] - nm);
      ladd += (p0 + p1) + (p2 + p3);
      pk0[mt] = pack_bf16(p0, p1);
      pk1[mt] = pack_bf16(p2, p3);
    }
    ladd += __shfl_xor(ladd, 16, 64);
    ladd += __shfl_xor(ladd, 32, 64);
    l = l * corr + ladd;
#pragma unroll
    for (int ct = 0; ct < 4; ct++)
#pragma unroll
      for (int r = 0; r < 4; r++) o[ct][r] *= corr;
    union U { unsigned u[4]; bf16x8 v; } pf[2];
    int sl0 = ((fq & 1) * 2) * 16 + fm;
    int sl1 = sl0 + 16;
    bool hi = fq >= 2;
#pragma unroll
    for (int f = 0; f < 2; f++) {
      unsigned a0 = (unsigned)__shfl((int)pk0[f * 2],     sl0, 64);
      unsigned b0 = (unsigned)__shfl((int)pk0[f * 2 + 1], sl0, 64);
      unsigned a1 = (unsigned)__shfl((int)pk1[f * 2],     sl0, 64);
      unsigned b1 = (unsigned)__shfl((int)pk1[f * 2 + 1], sl0, 64);
      unsigned a2 = (unsigned)__shfl((int)pk0[f * 2],     sl1, 64);
      unsigned b2 = (unsigned)__shfl((int)pk0[f * 2 + 1], sl1, 64);
      unsigned a3 = (unsigned)__shfl((int)pk1[f * 2],     sl1, 64);
      unsigned b3 = (unsigned)__shfl((int)pk1[f * 2 + 1], sl1, 64);
      pf[f].u[0] = hi ? b0 : a0;
      pf[f].u[1] = hi ? b1 : a1;
      pf[f].u[2] = hi ? b2 : a2;
      pf[f].u[3] = hi ? b3 : a3;
    }
#pragma unroll
    for (int ct = 0; ct < 4; ct++) {
      int row = ct * 16 + fm;
#pragma unroll
      for (int f = 0; f < 2; f++) {
        int kg = f * 4 + fq;
        bf16x8 vf = *(const bf16x8*)&Vs[row * 64 + ((kg ^ (row & 7)) * 8)];
        o[ct] = __builtin_amdgcn_mfma_f32_16x16x32_bf16(vf, pf[f].v, o[ct], 0, 0, 0);
      }
    }
    mx = nm;
  }
  float inv = 1.f / l;
  bf16_t* Op = O + (size_t)(b * 512 + q0 + fm) * 1024 + h * 64 + fq * 4;
#pragma unroll
  for (int ct = 0; ct < 4; ct++) {
    bf16x4 w4;
    w4[0] = (bf16_t)(o[ct][0] * inv);
    w4[1] = (bf16_t)(o[ct][1] * inv);
    w4[2] = (bf16_t)(o[ct][2] * inv);
    w4[3] = (bf16_t)(o[ct][3] * inv);
    *(bf16x4*)(Op + ct * 16) = w4;
  }
}

// ---------------- LayerNorm D=1024, bf16 in, OutT out -----------------------
template <typename OutT>
__global__ __launch_bounds__(256) void ln_kernel(
    const bf16_t* __restrict__ X, const float* __restrict__ gamma,
    const float* __restrict__ beta, OutT* __restrict__ Y) {
  __shared__ float red[8];
  int row = blockIdx.x;
  int tid = threadIdx.x;
  bf16x4 x4 = *(const bf16x4*)(X + (size_t)row * 1024 + tid * 4);
  float4 v = {(float)x4[0], (float)x4[1], (float)x4[2], (float)x4[3]};
  float s = (v.x + v.y) + (v.z + v.w);
  float ss = fmaf(v.x, v.x, fmaf(v.y, v.y, fmaf(v.z, v.z, v.w * v.w)));
#pragma unroll
  for (int off = 32; off > 0; off >>= 1) {
    s  += __shfl_down(s, off, 64);
    ss += __shfl_down(ss, off, 64);
  }
  if ((tid & 63) == 0) { red[tid >> 6] = s; red[4 + (tid >> 6)] = ss; }
  __syncthreads();
  float S  = (red[0] + red[1]) + (red[2] + red[3]);
  float SS = (red[4] + red[5]) + (red[6] + red[7]);
  float mu = S * (1.f / 1024.f);
  float var = SS * (1.f / 1024.f) - mu * mu;
  float inv = rsqrtf(var + 1e-5f);
  float4 g = *(const float4*)(gamma + tid * 4);
  float4 b = *(const float4*)(beta + tid * 4);
  float r0 = (v.x - mu) * inv * g.x + b.x;
  float r1 = (v.y - mu) * inv * g.y + b.y;
  float r2 = (v.z - mu) * inv * g.z + b.z;
  float r3 = (v.w - mu) * inv * g.w + b.w;
  OutT* yp = Y + (size_t)row * 1024 + tid * 4;
  yp[0] = (OutT)r0; yp[1] = (OutT)r1; yp[2] = (OutT)r2; yp[3] = (OutT)r3;
}

extern "C" void kernel_launch(void* const* d_in, const int* in_sizes, int n_in,
                              void* d_out, int out_size, void* d_ws, size_t ws_size,
                              hipStream_t stream) {
  (void)in_sizes; (void)n_in; (void)out_size; (void)ws_size;
  const float* x  = (const float*)d_in[0];
  const float* hh = (const float*)d_in[1];
  SrcPtrs sp;
  sp.p[0] = (const float*)d_in[2];  sp.p[1] = (const float*)d_in[4];
  sp.p[2] = (const float*)d_in[6];  sp.p[3] = (const float*)d_in[8];
  sp.p[4] = (const float*)d_in[10]; sp.p[5] = (const float*)d_in[12];
  sp.p[6] = (const float*)d_in[14]; sp.p[7] = (const float*)d_in[16];
  sp.p[8] = (const float*)d_in[20]; sp.p[9] = (const float*)d_in[22];
  const float* W1f = (const float*)d_in[20];
  const float* bq  = (const float*)d_in[3];
  const float* bk  = (const float*)d_in[5];
  const float* bv  = (const float*)d_in[7];
  const float* bo  = (const float*)d_in[9];
  const float* bck = (const float*)d_in[13];
  const float* bcv = (const float*)d_in[15];
  const float* bcq = (const float*)d_in[11];
  const float* bco = (const float*)d_in[17];
  const float* gamma = (const float*)d_in[18];
  const float* beta  = (const float*)d_in[19];
  const float* b1  = (const float*)d_in[21];
  const float* b2  = (const float*)d_in[23];
  float* out = (float*)d_out;
  char* ws = (char*)d_ws;
  const size_t MB = 1048576;

  bf16_t* wt[10];
  for (int i = 0; i < 10; i++) wt[i] = (bf16_t*)(ws + (size_t)i * 2 * MB);
  float* cb      = (float*)(ws + 20 * MB);        // [q|k|v|ck|cv|cq|0] x1024
  float* cb2     = (float*)(ws + 20 * MB + 32768);// fused FFN bias [1024]
  bf16_t* xb     = (bf16_t*)(ws + 21 * MB);  // 8MB; reused as t1n later
  bf16_t* hb     = (bf16_t*)(ws + 29 * MB);  // 8MB; reused as t2n later
  bf16_t* qkv    = (bf16_t*)(ws + 37 * MB);  // 24MB (dead after self_attn)
  bf16_t* kbuf   = (bf16_t*)(ws + 37 * MB);  // 8MB  (reuse qkv)
  bf16_t* vtbuf  = (bf16_t*)(ws + 45 * MB);  // 8MB  [1024][4096]
  bf16_t* cqbuf  = (bf16_t*)(ws + 61 * MB);  // 8MB
  bf16_t* attn   = (bf16_t*)(ws + 69 * MB);  // 8MB
  bf16_t* g4     = (bf16_t*)(ws + 77 * MB);  // 8MB; reused as f2out
  bf16_t* ptbuf  = (bf16_t*)(ws + 85 * MB);  // 2MB  Pt = (W1@W2)^T as Bt
  bf16_t* w1bf   = (bf16_t*)(ws + 87 * MB);  // 2MB  W1 bf16 (lives past qkv)
  bf16_t* t1n    = xb;
  bf16_t* t2n    = hb;
  bf16_t* f2out  = g4;

  // prep: casts, weight transposes, biases (+fused FFN bias)
  cast3_bf16_kernel<<<4608, 256, 0, stream>>>(x, hh, W1f, xb, w1bf);
  transpose_cast_all<<<dim3(32, 32, 10), dim3(32, 8), 0, stream>>>(sp, (bf16_t*)ws);
  prep_bias_kernel<<<32, 256, 0, stream>>>(bq, bk, bv, bck, bcv, bcq,
                                           wt[9], b1, b2, cb, cb2);

  // self-attn block; P-GEMM (FFN collapse) rides in the qkv dispatch
  gemm_qkv_p<<<dim3(28, 32), 256, 0, stream>>>(xb, wt[0], wt[9], w1bf, cb, qkv, ptbuf);
  self_attn_kernel<<<16384, 256, 0, stream>>>(qkv, attn);
  gemm_bf16<64, true, false><<<dim3(16, 32), 256, 0, stream>>>(attn, wt[3], bo, xb, g4, 1024);
  ln_kernel<bf16_t><<<4096, 256, 0, stream>>>(g4, gamma, beta, t1n);
  // cross-attn block (t1n == xb: written after xb's last read above)
  gemm_cqkv<<<dim3(48, 32), 256, 0, stream>>>(t1n, hb, wt[4], cb, cqbuf, kbuf, vtbuf);
  cross_attn_mfma<<<dim3(128, 8), 256, 0, stream>>>(cqbuf, kbuf, vtbuf, attn);
  gemm_bf16<64, true, false><<<dim3(16, 32), 256, 0, stream>>>(attn, wt[7], bco, t1n, g4, 1024);
  ln_kernel<bf16_t><<<4096, 256, 0, stream>>>(g4, gamma, beta, t2n);
  // FFN collapsed: out = t2n @ P + (b1@W2 + b2) + t2n
  gemm_bf16<64, true, false><<<dim3(16, 32), 256, 0, stream>>>(t2n, ptbuf, cb2, t2n, f2out, 1024);
  ln_kernel<float><<<4096, 256, 0, stream>>>(f2out, gamma, beta, out);
}

// Round 9
// 384.853 us; speedup vs baseline: 1.0655x; 1.0432x over previous
//
#include <hip/hip_runtime.h>

typedef __bf16 bf16_t;
typedef bf16_t bf16x8 __attribute__((ext_vector_type(8)));
typedef bf16_t bf16x4 __attribute__((ext_vector_type(4)));
typedef float f32x4 __attribute__((ext_vector_type(4)));

// async global->LDS 16B per lane. LDS dest = wave-uniform base + lane*16
// (m97/m104): per-lane pointers must be linear in lane index.
__device__ __forceinline__ void async_copy16(const void* g, void* l) {
  __builtin_amdgcn_global_load_lds(
      (const __attribute__((address_space(1))) unsigned int*)(unsigned long long)g,
      (__attribute__((address_space(3))) unsigned int*)(unsigned int)(unsigned long long)l,
      16, 0, 0);
}

__device__ __forceinline__ float fast_exp2(float x) {
#if __has_builtin(__builtin_amdgcn_exp2f)
  return __builtin_amdgcn_exp2f(x);
#else
  return exp2f(x);
#endif
}

__device__ __forceinline__ unsigned pack_bf16(float x, float y) {
  bf16_t lo = (bf16_t)x, hi = (bf16_t)y;
  unsigned short ul, uh;
  __builtin_memcpy(&ul, &lo, 2);
  __builtin_memcpy(&uh, &hi, 2);
  return (unsigned)ul | ((unsigned)uh << 16);
}

// ------- cast x,h -> xb|hb (contiguous) and W1 -> w1bf (separate dst) -------
__global__ __launch_bounds__(256) void cast3_bf16_kernel(
    const float* __restrict__ a, const float* __restrict__ b,
    const float* __restrict__ w1, bf16_t* __restrict__ dst1,
    bf16_t* __restrict__ dstw) {
  int i = (blockIdx.x * 256 + threadIdx.x) * 8;  // [0, 9M)
  const float* s;
  bf16_t* d;
  if (i < 4194304) { s = a + i; d = dst1 + i; }
  else if (i < 8388608) { s = b + i - 4194304; d = dst1 + i; }
  else { s = w1 + i - 8388608; d = dstw + (i - 8388608); }
  float4 u = *(const float4*)s;
  float4 v = *(const float4*)(s + 4);
  bf16x8 o;
  o[0]=(bf16_t)u.x; o[1]=(bf16_t)u.y; o[2]=(bf16_t)u.z; o[3]=(bf16_t)u.w;
  o[4]=(bf16_t)v.x; o[5]=(bf16_t)v.y; o[6]=(bf16_t)v.z; o[7]=(bf16_t)v.w;
  *(bf16x8*)d = o;
}

// ---------------- all-weights transpose+cast+scale (grid.z = weight idx) ----
struct SrcPtrs { const float* p[10]; };
__global__ __launch_bounds__(256) void transpose_cast_all(
    SrcPtrs srcs, bf16_t* __restrict__ dstbase) {
  __shared__ float tile[32][33];
  int z = blockIdx.z;
  const float* src = srcs.p[z];
  bf16_t* dst = dstbase + (size_t)z * 1048576;
  float scale = (z == 0) ? 0.125f : ((z == 4) ? 0.03125f : 1.f);
  int bx = blockIdx.x * 32;  // n base
  int by = blockIdx.y * 32;  // k base
  int tx = threadIdx.x, ty = threadIdx.y;
#pragma unroll
  for (int i = 0; i < 32; i += 8)
    tile[ty + i][tx] = src[(size_t)(by + ty + i) * 1024 + bx + tx];
  __syncthreads();
#pragma unroll
  for (int i = 0; i < 32; i += 8)
    dst[(size_t)(bx + ty + i) * 1024 + by + tx] = (bf16_t)(tile[tx][ty + i] * scale);
}

// --- bias concat [q|k|v|ck|cv|cq|zeros] x1024 + fused FFN bias (blk 28-31) --
__global__ __launch_bounds__(256) void prep_bias_kernel(
    const float* __restrict__ bq, const float* __restrict__ bk,
    const float* __restrict__ bv, const float* __restrict__ bck,
    const float* __restrict__ bcv, const float* __restrict__ bcq,
    const bf16_t* __restrict__ wt9, const float* __restrict__ b1,
    const float* __restrict__ b2, float* __restrict__ cb,
    float* __restrict__ cb2) {
  int bid = blockIdx.x;
  if (bid < 28) {
    int i = bid * 256 + threadIdx.x;
    if (i < 1024) cb[i] = bq[i] * 0.125f;
    else if (i < 2048) cb[i] = bk[i - 1024];
    else if (i < 3072) cb[i] = bv[i - 2048];
    else if (i < 4096) cb[i] = bck[i - 3072];
    else if (i < 5120) cb[i] = bcv[i - 4096];
    else if (i < 6144) cb[i] = bcq[i - 5120] * 0.03125f;
    else cb[i] = 0.f;  // zeros for the P-GEMM bias
  } else {
    // cb2[n] = sum_h b1[h]*W2[h][n] + b2[n];  wt9[n][h] = W2[h][n]
    int n = (bid - 28) * 256 + threadIdx.x;
    const bf16_t* row = wt9 + (size_t)n * 1024;
    float acc = 0.f;
#pragma unroll 4
    for (int h = 0; h < 1024; h += 8) {
      bf16x8 v = *(const bf16x8*)(row + h);
      float4 ba = *(const float4*)(b1 + h);
      float4 bb = *(const float4*)(b1 + h + 4);
      acc += ba.x*(float)v[0] + ba.y*(float)v[1] + ba.z*(float)v[2] + ba.w*(float)v[3]
           + bb.x*(float)v[4] + bb.y*(float)v[5] + bb.z*(float)v[6] + bb.w*(float)v[7];
    }
    cb2[n] = acc + b2[n];
  }
}

// ---------------- shared GEMM core: C[*,ldC] = A[*,1024] @ Bt[*,1024]^T -----
// 128xBN tile, BK=64, 4 waves, global_load_lds(16B), XOR-swizzled LDS.
// Epilogue: + bias[bn+local] (+ res) -> bf16; TRANS_OUT writes C^T (ldC = M).
template <int BN, int MI, bool HAS_RES, bool TRANS_OUT>
__device__ __forceinline__ void gemm_core(
    const bf16_t* __restrict__ A, const bf16_t* __restrict__ Bt,
    const float* __restrict__ bias, const bf16_t* __restrict__ res,
    bf16_t* __restrict__ C, int ldC, int bm, int bn,
    bf16_t* As, bf16_t* Bs) {
  constexpr int NI = 4;
  int tid = threadIdx.x;
  int w = tid >> 6, lane = tid & 63;
  int fm = lane & 15, fq = lane >> 4;
  int wm = (BN == 128) ? (w >> 1) * 64 : w * 32;
  int wn = (BN == 128) ? (w & 1) * 64 : 0;
  f32x4 acc[MI][NI] = {};
  for (int kt = 0; kt < 1024; kt += 64) {
#pragma unroll
    for (int i = 0; i < 4; i++) {  // A: 128 rows x 8 chunks
      int c = i * 256 + tid;
      int row = c >> 3, skg = (c & 7) ^ (row & 7);
      async_copy16(A + (size_t)(bm + row) * 1024 + kt + skg * 8, &As[c * 8]);
    }
#pragma unroll
    for (int i = 0; i < BN / 32; i++) {  // B: BN rows x 8 chunks
      int c = i * 256 + tid;
      int row = c >> 3, skg = (c & 7) ^ (row & 7);
      async_copy16(Bt + (size_t)(bn + row) * 1024 + kt + skg * 8, &Bs[c * 8]);
    }
    __syncthreads();  // drains vmcnt(0): copies visible
#pragma unroll
    for (int ks = 0; ks < 2; ks++) {
      bf16x8 af[MI], bfr[NI];
      int kg = ks * 4 + fq;
#pragma unroll
      for (int mi = 0; mi < MI; mi++) {
        int row = wm + mi * 16 + fm;
        af[mi] = *(const bf16x8*)&As[row * 64 + ((kg ^ (row & 7)) * 8)];
      }
#pragma unroll
      for (int ni = 0; ni < NI; ni++) {
        int row = wn + ni * 16 + fm;
        bfr[ni] = *(const bf16x8*)&Bs[row * 64 + ((kg ^ (row & 7)) * 8)];
      }
#pragma unroll
      for (int mi = 0; mi < MI; mi++)
#pragma unroll
        for (int ni = 0; ni < NI; ni++)
          acc[mi][ni] = __builtin_amdgcn_mfma_f32_16x16x32_bf16(
              af[mi], bfr[ni], acc[mi][ni], 0, 0, 0);
    }
    __syncthreads();  // protect LDS reuse
  }
#pragma unroll
  for (int mi = 0; mi < MI; mi++) {
#pragma unroll
    for (int ni = 0; ni < NI; ni++) {
      int col = bn + wn + ni * 16 + fm;
      float bv = bias[col];
      if (TRANS_OUT) {
        int rowb = bm + wm + mi * 16 + fq * 4;
        bf16x4 w4;
#pragma unroll
        for (int r = 0; r < 4; r++) w4[r] = (bf16_t)(acc[mi][ni][r] + bv);
        *(bf16x4*)&C[(size_t)col * ldC + rowb] = w4;  // C^T: ldC = M
      } else {
#pragma unroll
        for (int r = 0; r < 4; r++) {
          int row = bm + wm + mi * 16 + fq * 4 + r;  // C/D map (m89/m91)
          float v = acc[mi][ni][r] + bv;
          if (HAS_RES) v += (float)res[(size_t)row * ldC + col];
          C[(size_t)row * ldC + col] = (bf16_t)v;
        }
      }
    }
  }
}

// XCD swizzle: hw assigns blocks round-robin by linear id (xcd = lin&7 when
// gridX%8==0 -> degenerate bn-partition; R7 FETCH 71.7MB == 64MB A-refetch +
// 6MB B confirms). Remap to 4 bm-groups x 2 bn-groups: per-XCD working set
// (A-slice + B-slice) ~3MB fits the 4MiB L2; chip fetch = A*2 + B*4 (min).
template <int GX, int GY, int BN>
__device__ __forceinline__ void xcd_map(int lin, int& bm, int& bn) {
  constexpr int HX = GX / 2, QY = GY / 4;
  int xcd = lin & 7, idx = lin >> 3;
  int ly = idx / HX, lx = idx - ly * HX;
  bm = ((xcd >> 1) * QY + ly) * 128;
  bn = ((xcd & 1) * HX + lx) * BN;
}

// ---------------- standalone GEMM kernel (BN=64, grid (16,32) swizzled) -----
template <bool HAS_RES, bool TRANS_OUT>
__global__ __launch_bounds__(256) void gemm_bf16(
    const bf16_t* __restrict__ A, const bf16_t* __restrict__ Bt,
    const float* __restrict__ bias, const bf16_t* __restrict__ res,
    bf16_t* __restrict__ C, int ldC) {
  __shared__ bf16_t As[128 * 64];
  __shared__ bf16_t Bs[64 * 64];
  int bm, bn;
  xcd_map<16, 32, 64>(blockIdx.x + 16 * blockIdx.y, bm, bn);
  gemm_core<64, 2, HAS_RES, TRANS_OUT>(A, Bt, bias, res, C, ldC, bm, bn, As, Bs);
}

// -------- qkv (BN=128, z=0, swizzled) + FFN-collapse P-GEMM (z=1 tail) ------
// qkv: C[4096][3072] = xb @ [Wq|Wk|Wv], grid (24,32,2).
// P:   Pt[1024][1024] = wt9 @ w1bf^T; 128 blocks of the z=1 plane (rest exit).
__global__ __launch_bounds__(256) void gemm_qkv_p(
    const bf16_t* __restrict__ xb, const bf16_t* __restrict__ wt0,
    const bf16_t* __restrict__ wt9, const bf16_t* __restrict__ w1bf,
    const float* __restrict__ cb, bf16_t* __restrict__ qkv,
    bf16_t* __restrict__ pt) {
  __shared__ bf16_t smem[2 * 128 * 64];  // 32 KB
  int lin = blockIdx.x + 24 * blockIdx.y;
  if (blockIdx.z == 0) {
    int bm, bn;
    xcd_map<24, 32, 128>(lin, bm, bn);
    gemm_core<128, 4, false, false>(xb, wt0, cb, nullptr, qkv, 3072,
                                    bm, bn, smem, smem + 128 * 64);
  } else {
    if (lin >= 128) return;
    gemm_core<64, 2, false, false>(wt9, w1bf, cb + 6144, nullptr, pt, 1024,
                                   (lin >> 4) * 128, (lin & 15) * 64,
                                   smem, smem + 128 * 64);
  }
}

// ---------------- merged cq / ck / cv projections (BN=64, grid (48,32)) -----
// gx = swizzled global col 0..47; region = gx>>4: 0 -> cq = t1n@Wcq,
// 1 -> K = hb@Wck, 2 -> V^T = (hb@Wcv)^T (ldC=4096). wt[4..6] contig at wt4.
__global__ __launch_bounds__(256) void gemm_cqkv(
    const bf16_t* __restrict__ t1n, const bf16_t* __restrict__ hb,
    const bf16_t* __restrict__ wt4, const float* __restrict__ cb,
    bf16_t* __restrict__ cq, bf16_t* __restrict__ kbuf,
    bf16_t* __restrict__ vt) {
  __shared__ bf16_t As[128 * 64];
  __shared__ bf16_t Bs[64 * 64];
  int lin = blockIdx.x + 48 * blockIdx.y;
  int xcd = lin & 7, idx = lin >> 3;
  int ly = idx / 24, lx = idx - ly * 24;        // HX=24, QY=8
  int bm = ((xcd >> 1) * 8 + ly) * 128;
  int gx = (xcd & 1) * 24 + lx;                 // 0..47
  int region = gx >> 4;
  int bn = (gx & 15) * 64;
  const bf16_t* Bt = wt4 + (size_t)region * 1048576;
  if (region == 2) {
    gemm_core<64, 2, false, true>(hb, Bt, cb + 4096, nullptr, vt, 4096,
                                  bm, bn, As, Bs);
  } else if (region == 1) {
    gemm_core<64, 2, false, false>(hb, Bt, cb + 3072, nullptr, kbuf, 1024,
                                   bm, bn, As, Bs);
  } else {
    gemm_core<64, 2, false, false>(t1n, Bt, cb + 5120, nullptr, cq, 1024,
                                   bm, bn, As, Bs);
  }
}

// ---------------- self-attn core: causal softmax over C=64 channels ---------
// QKV packed [4096][3072] bf16 (Q|K|V), O [4096][1024] bf16. Q pre-scaled 1/8.
// K,V staged once to LDS as f32 pairs; uniform-address ds_read broadcasts
// (conflict-free, prefetchable). 2-way split accumulators (R6-verified best).
__global__ __launch_bounds__(256) void self_attn_kernel(
    const bf16_t* __restrict__ QKV, bf16_t* __restrict__ O) {
  __shared__ float2 kv[4][64];
  int tid = threadIdx.x;
  int wu = tid >> 6, lane = tid & 63;
  int unit = blockIdx.x * 4 + wu;  // m*16 + h
  int m = unit >> 4, h = unit & 15;
  size_t iq = (size_t)m * 3072 + h * 64 + lane;
  float q = (float)QKV[iq] * 1.44269504089f;
  float kk = (float)QKV[iq + 1024];
  float vv = (float)QKV[iq + 2048];
  kv[wu][lane] = make_float2(kk, vv);
  __syncthreads();
  const float2* kvp = kv[wu];
  float l0 = 0.f, l1 = 0.f, o0 = 0.f, o1 = 0.f;
#pragma unroll
  for (int j = 0; j < 64; j += 2) {
    float2 a = kvp[j];      // uniform-address LDS broadcast
    float2 b = kvp[j + 1];
    float e0 = fast_exp2(q * a.x);
    float e1 = fast_exp2(q * b.x);
    e0 = (j <= lane) ? e0 : 0.f;
    e1 = (j + 1 <= lane) ? e1 : 0.f;
    l0 += e0; o0 = fmaf(e0, a.y, o0);
    l1 += e1; o1 = fmaf(e1, b.y, o1);
  }
  float l = l0 + l1, o = o0 + o1;
  O[(size_t)m * 1024 + h * 64 + lane] = (bf16_t)(o / l);
}

// ---------------- cross-attn, MFMA flash ------------------------------------
// Per block: one (b,h), 64 q-rows; 4 waves x 16 q-rows. K-tile = 64.
// S^T = K.Q^T  (A=K rows from LDS, B=Q rows in regs) -> stats per q=lane&15.
// O^T = Vt.P^T (A=Vt rows from LDS, B=P^T via shfl+select transform).
// Q prescaled 1/32. Kb [4096][1024]; Vt [1024][4096]; O [4096][1024].
__global__ __launch_bounds__(256) void cross_attn_mfma(
    const bf16_t* __restrict__ Q, const bf16_t* __restrict__ Kb,
    const bf16_t* __restrict__ Vt, bf16_t* __restrict__ O) {
  __shared__ bf16_t Ks[64 * 64];
  __shared__ bf16_t Vs[64 * 64];
  int tid = threadIdx.x;
  int w = tid >> 6, lane = tid & 63;
  int fm = lane & 15, fq = lane >> 4;
  int bh = blockIdx.x;
  int b = bh >> 4, h = bh & 15;
  int q0 = blockIdx.y * 64 + w * 16;
  const bf16_t* Qp = Q + (size_t)(b * 512 + q0 + fm) * 1024 + h * 64 + fq * 8;
  bf16x8 qf0 = *(const bf16x8*)Qp;
  bf16x8 qf1 = *(const bf16x8*)(Qp + 32);
  f32x4 o[4] = {};  // O^T tiles ct: lane holds O^T[c=ct*16+fq*4+r][q=fm]
  float mx = -1e30f, l = 0.f;
  for (int k0 = 0; k0 < 512; k0 += 64) {
    __syncthreads();  // previous tile's LDS reads complete
#pragma unroll
    for (int i = 0; i < 2; i++) {  // 64 rows x 8 chunks, XOR swizzle
      int c = i * 256 + tid;
      int row = c >> 3, kg = (c & 7) ^ (row & 7);
      async_copy16(Kb + (size_t)(b * 512 + k0 + row) * 1024 + h * 64 + kg * 8,
                   &Ks[c * 8]);
      async_copy16(Vt + (size_t)(h * 64 + row) * 4096 + b * 512 + k0 + kg * 8,
                   &Vs[c * 8]);
    }
    __syncthreads();  // drain global_load_lds
    // S^T tiles mt: lane holds S^T[k=mt*16+fq*4+r][q=fm]
    f32x4 s[4] = {};
#pragma unroll
    for (int mt = 0; mt < 4; mt++) {
      int row = mt * 16 + fm;
#pragma unroll
      for (int f = 0; f < 2; f++) {
        int kg = f * 4 + fq;
        bf16x8 kf = *(const bf16x8*)&Ks[row * 64 + ((kg ^ (row & 7)) * 8)];
        s[mt] = __builtin_amdgcn_mfma_f32_16x16x32_bf16(
            kf, (f ? qf1 : qf0), s[mt], 0, 0, 0);
      }
    }
    // online softmax (stats per q=fm, replicated across quads)
    float smax = -1e30f;
#pragma unroll
    for (int mt = 0; mt < 4; mt++)
#pragma unroll
      for (int r = 0; r < 4; r++) smax = fmaxf(smax, s[mt][r]);
    smax = fmaxf(smax, __shfl_xor(smax, 16, 64));
    smax = fmaxf(smax, __shfl_xor(smax, 32, 64));
    float nm = fmaxf(mx, smax);
    float corr = __expf(mx - nm);
    float ladd = 0.f;
    unsigned pk0[4], pk1[4];
#pragma unroll
    for (int mt = 0; mt < 4; mt++) {
      float p0 = __expf(s[mt][0] - nm);
      float p1 = __expf(s[mt][1] - nm);
      float p2 = __expf(s[mt][2] - nm);
      float p3 = __expf(s[mt][3] - nm);
      ladd += (p0 + p1) + (p2 + p3);
      pk0[mt] = pack_bf16(p0, p1);
      pk1[mt] = pack_bf16(p2, p3);
    }
    ladd += __shfl_xor(ladd, 16, 64);
    ladd += __shfl_xor(ladd, 32, 64);
    l = l * corr + ladd;
#pragma unroll
    for (int ct = 0; ct < 4; ct++)
#pragma unroll
      for (int r = 0; r < 4; r++) o[ct][r] *= corr;
    union U { unsigned u[4]; bf16x8 v; } pf[2];
    int sl0 = ((fq & 1) * 2) * 16 + fm;
    int sl1 = sl0 + 16;
    bool hi = fq >= 2;
#pragma unroll
    for (int f = 0; f < 2; f++) {
      unsigned a0 = (unsigned)__shfl((int)pk0[f * 2],     sl0, 64);
      unsigned b0 = (unsigned)__shfl((int)pk0[f * 2 + 1], sl0, 64);
      unsigned a1 = (unsigned)__shfl((int)pk1[f * 2],     sl0, 64);
      unsigned b1 = (unsigned)__shfl((int)pk1[f * 2 + 1], sl0, 64);
      unsigned a2 = (unsigned)__shfl((int)pk0[f * 2],     sl1, 64);
      unsigned b2 = (unsigned)__shfl((int)pk0[f * 2 + 1], sl1, 64);
      unsigned a3 = (unsigned)__shfl((int)pk1[f * 2],     sl1, 64);
      unsigned b3 = (unsigned)__shfl((int)pk1[f * 2 + 1], sl1, 64);
      pf[f].u[0] = hi ? b0 : a0;
      pf[f].u[1] = hi ? b1 : a1;
      pf[f].u[2] = hi ? b2 : a2;
      pf[f].u[3] = hi ? b3 : a3;
    }
#pragma unroll
    for (int ct = 0; ct < 4; ct++) {
      int row = ct * 16 + fm;
#pragma unroll
      for (int f = 0; f < 2; f++) {
        int kg = f * 4 + fq;
        bf16x8 vf = *(const bf16x8*)&Vs[row * 64 + ((kg ^ (row & 7)) * 8)];
        o[ct] = __builtin_amdgcn_mfma_f32_16x16x32_bf16(vf, pf[f].v, o[ct], 0, 0, 0);
      }
    }
    mx = nm;
  }
  float inv = 1.f / l;
  bf16_t* Op = O + (size_t)(b * 512 + q0 + fm) * 1024 + h * 64 + fq * 4;
#pragma unroll
  for (int ct = 0; ct < 4; ct++) {
    bf16x4 w4;
    w4[0] = (bf16_t)(o[ct][0] * inv);
    w4[1] = (bf16_t)(o[ct][1] * inv);
    w4[2] = (bf16_t)(o[ct][2] * inv);
    w4[3] = (bf16_t)(o[ct][3] * inv);
    *(bf16x4*)(Op + ct * 16) = w4;
  }
}

// ---------------- LayerNorm D=1024, bf16 in, OutT out -----------------------
template <typename OutT>
__global__ __launch_bounds__(256) void ln_kernel(
    const bf16_t* __restrict__ X, const float* __restrict__ gamma,
    const float* __restrict__ beta, OutT* __restrict__ Y) {
  __shared__ float red[8];
  int row = blockIdx.x;
  int tid = threadIdx.x;
  bf16x4 x4 = *(const bf16x4*)(X + (size_t)row * 1024 + tid * 4);
  float4 v = {(float)x4[0], (float)x4[1], (float)x4[2], (float)x4[3]};
  float s = (v.x + v.y) + (v.z + v.w);
  float ss = fmaf(v.x, v.x, fmaf(v.y, v.y, fmaf(v.z, v.z, v.w * v.w)));
#pragma unroll
  for (int off = 32; off > 0; off >>= 1) {
    s  += __shfl_down(s, off, 64);
    ss += __shfl_down(ss, off, 64);
  }
  if ((tid & 63) == 0) { red[tid >> 6] = s; red[4 + (tid >> 6)] = ss; }
  __syncthreads();
  float S  = (red[0] + red[1]) + (red[2] + red[3]);
  float SS = (red[4] + red[5]) + (red[6] + red[7]);
  float mu = S * (1.f / 1024.f);
  float var = SS * (1.f / 1024.f) - mu * mu;
  float inv = rsqrtf(var + 1e-5f);
  float4 g = *(const float4*)(gamma + tid * 4);
  float4 b = *(const float4*)(beta + tid * 4);
  float r0 = (v.x - mu) * inv * g.x + b.x;
  float r1 = (v.y - mu) * inv * g.y + b.y;
  float r2 = (v.z - mu) * inv * g.z + b.z;
  float r3 = (v.w - mu) * inv * g.w + b.w;
  OutT* yp = Y + (size_t)row * 1024 + tid * 4;
  yp[0] = (OutT)r0; yp[1] = (OutT)r1; yp[2] = (OutT)r2; yp[3] = (OutT)r3;
}

extern "C" void kernel_launch(void* const* d_in, const int* in_sizes, int n_in,
                              void* d_out, int out_size, void* d_ws, size_t ws_size,
                              hipStream_t stream) {
  (void)in_sizes; (void)n_in; (void)out_size; (void)ws_size;
  const float* x  = (const float*)d_in[0];
  const float* hh = (const float*)d_in[1];
  SrcPtrs sp;
  sp.p[0] = (const float*)d_in[2];  sp.p[1] = (const float*)d_in[4];
  sp.p[2] = (const float*)d_in[6];  sp.p[3] = (const float*)d_in[8];
  sp.p[4] = (const float*)d_in[10]; sp.p[5] = (const float*)d_in[12];
  sp.p[6] = (const float*)d_in[14]; sp.p[7] = (const float*)d_in[16];
  sp.p[8] = (const float*)d_in[20]; sp.p[9] = (const float*)d_in[22];
  const float* W1f = (const float*)d_in[20];
  const float* bq  = (const float*)d_in[3];
  const float* bk  = (const float*)d_in[5];
  const float* bv  = (const float*)d_in[7];
  const float* bo  = (const float*)d_in[9];
  const float* bck = (const float*)d_in[13];
  const float* bcv = (const float*)d_in[15];
  const float* bcq = (const float*)d_in[11];
  const float* bco = (const float*)d_in[17];
  const float* gamma = (const float*)d_in[18];
  const float* beta  = (const float*)d_in[19];
  const float* b1  = (const float*)d_in[21];
  const float* b2  = (const float*)d_in[23];
  float* out = (float*)d_out;
  char* ws = (char*)d_ws;
  const size_t MB = 1048576;

  bf16_t* wt[10];
  for (int i = 0; i < 10; i++) wt[i] = (bf16_t*)(ws + (size_t)i * 2 * MB);
  float* cb      = (float*)(ws + 20 * MB);        // [q|k|v|ck|cv|cq|0] x1024
  float* cb2     = (float*)(ws + 20 * MB + 32768);// fused FFN bias [1024]
  bf16_t* xb     = (bf16_t*)(ws + 21 * MB);  // 8MB; reused as t1n later
  bf16_t* hb     = (bf16_t*)(ws + 29 * MB);  // 8MB; reused as t2n later
  bf16_t* qkv    = (bf16_t*)(ws + 37 * MB);  // 24MB (dead after self_attn)
  bf16_t* kbuf   = (bf16_t*)(ws + 37 * MB);  // 8MB  (reuse qkv)
  bf16_t* vtbuf  = (bf16_t*)(ws + 45 * MB);  // 8MB  [1024][4096]
  bf16_t* cqbuf  = (bf16_t*)(ws + 61 * MB);  // 8MB
  bf16_t* attn   = (bf16_t*)(ws + 69 * MB);  // 8MB
  bf16_t* g4     = (bf16_t*)(ws + 77 * MB);  // 8MB; reused as f2out
  bf16_t* ptbuf  = (bf16_t*)(ws + 85 * MB);  // 2MB  Pt = (W1@W2)^T as Bt
  bf16_t* w1bf   = (bf16_t*)(ws + 87 * MB);  // 2MB  W1 bf16 (lives past qkv)
  bf16_t* t1n    = xb;
  bf16_t* t2n    = hb;
  bf16_t* f2out  = g4;

  // prep: casts, weight transposes, biases (+fused FFN bias)
  cast3_bf16_kernel<<<4608, 256, 0, stream>>>(x, hh, W1f, xb, w1bf);
  transpose_cast_all<<<dim3(32, 32, 10), dim3(32, 8), 0, stream>>>(sp, (bf16_t*)ws);
  prep_bias_kernel<<<32, 256, 0, stream>>>(bq, bk, bv, bck, bcv, bcq,
                                           wt[9], b1, b2, cb, cb2);

  // self-attn block; P-GEMM (FFN collapse) rides the z=1 tail of qkv
  gemm_qkv_p<<<dim3(24, 32, 2), 256, 0, stream>>>(xb, wt[0], wt[9], w1bf, cb, qkv, ptbuf);
  self_attn_kernel<<<16384, 256, 0, stream>>>(qkv, attn);
  gemm_bf16<true, false><<<dim3(16, 32), 256, 0, stream>>>(attn, wt[3], bo, xb, g4, 1024);
  ln_kernel<bf16_t><<<4096, 256, 0, stream>>>(g4, gamma, beta, t1n);
  // cross-attn block (t1n == xb: written after xb's last read above)
  gemm_cqkv<<<dim3(48, 32), 256, 0, stream>>>(t1n, hb, wt[4], cb, cqbuf, kbuf, vtbuf);
  cross_attn_mfma<<<dim3(128, 8), 256, 0, stream>>>(cqbuf, kbuf, vtbuf, attn);
  gemm_bf16<true, false><<<dim3(16, 32), 256, 0, stream>>>(attn, wt[7], bco, t1n, g4, 1024);
  ln_kernel<bf16_t><<<4096, 256, 0, stream>>>(g4, gamma, beta, t2n);
  // FFN collapsed: out = t2n @ P + (b1@W2 + b2) + t2n
  gemm_bf16<true, false><<<dim3(16, 32), 256, 0, stream>>>(t2n, ptbuf, cb2, t2n, f2out, 1024);
  ln_kernel<float><<<4096, 256, 0, stream>>>(f2out, gamma, beta, out);
}